// Round 6
// baseline (1140.284 us; speedup 1.0000x reference)
//
#include <hip/hip_runtime.h>
#include <hip/hip_bf16.h>
#include <math.h>

// Problem constants (B=4, S=2048 -> T=8192 tokens)
#define T_TOK 8192
#define DM    1024
#define NE    8
#define HD    4096

typedef __bf16 bf16;
typedef __attribute__((ext_vector_type(8))) __bf16 bf16x8;
typedef __attribute__((ext_vector_type(4))) float  f32x4;

__device__ __forceinline__ void gl_lds16(const void* g, void* l) {
  __builtin_amdgcn_global_load_lds((const __attribute__((address_space(1))) void*)g,
                                   (__attribute__((address_space(3))) void*)l, 16, 0, 0);
}

#define RAW_BARRIER() asm volatile("s_barrier" ::: "memory")
#define VMCNT0()      asm volatile("s_waitcnt vmcnt(0)" ::: "memory")

__device__ __forceinline__ int imin(int a, int b) { return a < b ? a : b; }

// ---------------- zero out + counts ----------------
__global__ void zero_kernel(float* __restrict__ out, int* __restrict__ counts) {
  size_t stride = (size_t)gridDim.x * blockDim.x;
  size_t n4 = (size_t)T_TOK * DM / 4;
  for (size_t i = (size_t)blockIdx.x * blockDim.x + threadIdx.x; i < n4; i += stride) {
    float4 z = {0.f, 0.f, 0.f, 0.f};
    ((float4*)out)[i] = z;
  }
  if (blockIdx.x == 0 && threadIdx.x < NE) counts[threadIdx.x] = 0;
}

// ---------------- transpose + cvt: in [e][R][C] fp32 -> out [e][C][R] bf16 ----------------
__global__ void transpose_cvt_kernel(const float* __restrict__ in, bf16* __restrict__ out,
                                     int R, int C) {
  __shared__ float tile[64][65];
  int e = blockIdx.z;
  int c0 = blockIdx.x * 64, r0 = blockIdx.y * 64;
  int tid = threadIdx.x;
  int lr = tid >> 2, lc = (tid & 3) * 16;
  const float* src = in + ((size_t)e * R + r0 + lr) * C + c0 + lc;
#pragma unroll
  for (int q = 0; q < 4; ++q) {
    float4 v = *(const float4*)(src + q * 4);
    tile[lr][lc + q * 4 + 0] = v.x;
    tile[lr][lc + q * 4 + 1] = v.y;
    tile[lr][lc + q * 4 + 2] = v.z;
    tile[lr][lc + q * 4 + 3] = v.w;
  }
  __syncthreads();
  int oc = tid >> 3;      // 0..31
  int rchunk = tid & 7;   // 0..7
#pragma unroll
  for (int q = 0; q < 2; ++q) {
    int ocq = oc + q * 32;
    bf16x8 o;
#pragma unroll
    for (int k = 0; k < 8; ++k) o[k] = (bf16)tile[rchunk * 8 + k][ocq];
    *(bf16x8*)(out + ((size_t)e * C + c0 + ocq) * R + r0 + rchunk * 8) = o;
  }
}

// ---------------- gating: logits (double), softmax, top-2, compaction + x->bf16 ----------------
__global__ void gating_kernel(const float* __restrict__ x, const float* __restrict__ Wg,
                              const float* __restrict__ bg, int* __restrict__ counts,
                              int* __restrict__ tokl, float* __restrict__ wgt,
                              bf16* __restrict__ xb) {
  int t = blockIdx.x * 4 + (threadIdx.x >> 6);
  int lane = threadIdx.x & 63;
  if (t >= T_TOK) return;
  double acc[NE];
#pragma unroll
  for (int e = 0; e < NE; ++e) acc[e] = 0.0;
  const float* xr = x + (size_t)t * DM;
  bf16* xbr = xb + (size_t)t * DM;
  for (int d = lane; d < DM; d += 64) {
    float xv = xr[d];
    xbr[d] = (bf16)xv;   // fused fp32->bf16 conversion
#pragma unroll
    for (int e = 0; e < NE; ++e) acc[e] += (double)xv * (double)Wg[d * NE + e];
  }
#pragma unroll
  for (int e = 0; e < NE; ++e)
    for (int o = 32; o > 0; o >>= 1) acc[e] += __shfl_down(acc[e], o, 64);
  if (lane == 0) {
    float l[NE], w[NE];
    float m = -1e30f;
#pragma unroll
    for (int e = 0; e < NE; ++e) { l[e] = (float)acc[e] + bg[e]; m = fmaxf(m, l[e]); }
    float s = 0.f;
#pragma unroll
    for (int e = 0; e < NE; ++e) { w[e] = expf(l[e] - m); s += w[e]; }
    float inv = 1.f / s;
#pragma unroll
    for (int e = 0; e < NE; ++e) w[e] *= inv;
    int e1 = 0; float v1 = w[0];
#pragma unroll
    for (int e = 1; e < NE; ++e) if (w[e] > v1) { v1 = w[e]; e1 = e; }
    int e2 = -1; float v2 = -1.f;
#pragma unroll
    for (int e = 0; e < NE; ++e) if (e != e1 && w[e] > v2) { v2 = w[e]; e2 = e; }
    int s1 = atomicAdd(&counts[e1], 1);
    tokl[e1 * T_TOK + s1] = t; wgt[e1 * T_TOK + s1] = v1;
    int s2 = atomicAdd(&counts[e2], 1);
    tokl[e2 * T_TOK + s2] = t; wgt[e2 * T_TOK + s2] = v2;
  }
}

// ---------------- scan ----------------
__global__ void scan_kernel(const int* __restrict__ counts, int* __restrict__ offsets) {
  if (threadIdx.x == 0 && blockIdx.x == 0) {
    int s = 0;
#pragma unroll
    for (int e = 0; e < NE; ++e) { offsets[e] = s; s += counts[e]; }
    offsets[NE] = s;
  }
}

// =====================================================================================
// 256x256 tile, BK=64, 512 thr (8 waves, wm=w&1 wn=w>>1), 128 KB LDS dbuf.
// T3-MINIMUM single-barrier loop (m248-V1 class): per K-tile
//   { if(k+1<K) issue 8 gl_lds for tile k+1 -> buf^1;            // latency cover
//     ds_read all fragments from buf (compiler inserts partial lgkmcnt under MFMAs);
//     setprio(1) 32 MFMA setprio(0); af reload; setprio(1) 32 MFMA setprio(0);
//     vmcnt(0);   // own stage loads landed (issued ~2.5k cyc ago -> near-zero stall)
//     s_barrier;  // ONE barrier per K-tile: everyone's stage landed, all reads done
//   }
// No mid-tile barriers -> waves skew freely, one wave's ds_reads overlap another's
// MFMA. No manual lgkm pins (m141 lesson). WAR safe: reads are register-delivered
// before their consuming MFMA, which precedes the barrier; next stage issues after.
// No dummy last-tile refetch (saves ~67 MB junk fetch per launch).
// T2 XOR swizzle (pre-swizzled gl_lds source + swizzled ds_read col): 0 conflicts.
// XCD-bijective block map: expert e pinned to XCD e; B panels L2-resident.
// =====================================================================================

#define LDA_F(IH, CB) \
  _Pragma("unroll") for (int kh = 0; kh < 2; ++kh) \
  _Pragma("unroll") for (int i = 0; i < 4; ++i) \
    af[kh*4+i] = *(const bf16x8*)(Ab + (CB) + (128*(IH) + 64*wm + 16*i + lf) * 128 + (colx ^ (kh*64)));

#define LDB_F(BF, JH, CB) \
  _Pragma("unroll") for (int kh = 0; kh < 2; ++kh) \
  _Pragma("unroll") for (int j = 0; j < 2; ++j) \
    BF[kh*2+j] = *(const bf16x8*)(Bb + (CB) + (128*(JH) + 32*wn + 16*j + lf) * 128 + (colx ^ (kh*64)));

#define MM_F(IH, JH, BF) \
  _Pragma("unroll") for (int kh = 0; kh < 2; ++kh) \
  _Pragma("unroll") for (int i = 0; i < 4; ++i) \
  _Pragma("unroll") for (int j = 0; j < 2; ++j) \
    acc[IH][JH][i][j] = __builtin_amdgcn_mfma_f32_16x16x32_bf16(af[kh*4+i], BF[kh*2+j], acc[IH][JH][i][j], 0, 0, 0);

#define ISSUE_A(H, NBO, KB) do { \
    gl_lds16(gA[2*(H)] + (KB), Al + (NBO) + (H)*16384 + dst); \
    gl_lds16(gA[2*(H)+1] + (KB), Al + (NBO) + (H)*16384 + 8192 + dst); \
  } while (0)
#define ISSUE_B(H, NBO, KB) do { \
    gl_lds16(gB[2*(H)] + (KB), Bl + (NBO) + (H)*16384 + dst); \
    gl_lds16(gB[2*(H)+1] + (KB), Bl + (NBO) + (H)*16384 + 8192 + dst); \
  } while (0)

#define KTILE_BODY(CB, NBO, KB, STG) \
    if (STG) { \
      ISSUE_A(0, NBO, KB); ISSUE_B(0, NBO, KB); \
      ISSUE_B(1, NBO, KB); ISSUE_A(1, NBO, KB); \
    } \
    LDA_F(0, CB); \
    LDB_F(bfr0, 0, CB); \
    LDB_F(bfr1, 1, CB); \
    __builtin_amdgcn_s_setprio(1); \
    MM_F(0, 0, bfr0); \
    MM_F(0, 1, bfr1); \
    __builtin_amdgcn_s_setprio(0); \
    LDA_F(1, CB); \
    __builtin_amdgcn_s_setprio(1); \
    MM_F(1, 0, bfr0); \
    MM_F(1, 1, bfr1); \
    __builtin_amdgcn_s_setprio(0); \
    VMCNT0(); \
    RAW_BARRIER();

__global__ __launch_bounds__(512, 2) void gemm1_kernel(
    const bf16* __restrict__ xbf, const bf16* __restrict__ w1t,
    const float* __restrict__ b1, const int* __restrict__ counts,
    const int* __restrict__ offsets, const int* __restrict__ tokl,
    bf16* __restrict__ hbuf, int Hc, int cbase) {
  int bid = blockIdx.x;
  int q = gridDim.x >> 3;
  int L = (bid & 7) * q + (bid >> 3);
  int rt = L & 31;
  int g = L >> 5;
  int NT = Hc >> 8;
  int nt = g % NT, e = g / NT;
  int cnt = counts[e];
  if (rt * 256 >= cnt) return;
  __shared__ __align__(16) bf16 sA[2][256 * 64];
  __shared__ __align__(16) bf16 sB[2][256 * 64];
  int tid = threadIdx.x, lane = tid & 63, w = tid >> 6;
  int wm = w & 1, wn = w >> 1;
  int lf = lane & 15;
  int colx = ((lane >> 4) * 16) ^ ((lane & 7) << 4);
  int ra = tid >> 3;
  int ko = (tid & 7) * 16;
  int kox = ko ^ ((ra & 7) << 4);
  int dst = w * 1024;
  int hoff = offsets[e];
  const char* gA[4];
  const char* gB[4];
#pragma unroll
  for (int s = 0; s < 4; ++s) {
    int r = imin(rt * 256 + ra + s * 64, cnt - 1);
    int t = tokl[e * T_TOK + r];
    gA[s] = (const char*)(xbf + (size_t)t * DM) + kox;
    int col = cbase + nt * 256 + ra + s * 64;
    gB[s] = (const char*)(w1t + ((size_t)e * HD + col) * DM) + kox;
  }
  char* Al = (char*)sA;
  char* Bl = (char*)sB;
  const char* Ab = (const char*)sA;
  const char* Bb = (const char*)sB;
  f32x4 acc[2][2][4][2];
#pragma unroll
  for (int ih = 0; ih < 2; ++ih)
#pragma unroll
    for (int jh = 0; jh < 2; ++jh)
#pragma unroll
      for (int i = 0; i < 4; ++i)
#pragma unroll
        for (int j = 0; j < 2; ++j) acc[ih][jh][i][j] = {0.f, 0.f, 0.f, 0.f};
  bf16x8 af[8], bfr0[4], bfr1[4];
  const int K = DM / 64;  // 16
  // prologue: stage tile 0 into buf 0, drain, converge
  ISSUE_A(0, 0, 0); ISSUE_B(0, 0, 0); ISSUE_B(1, 0, 0); ISSUE_A(1, 0, 0);
  VMCNT0();
  RAW_BARRIER();
  for (int k = 0; k < K; ++k) {
    int cb = (k & 1) * 32768;
    int nbo = ((k + 1) & 1) * 32768;
    int kb = (k + 1) * 128;
    KTILE_BODY(cb, nbo, kb, (k + 1 < K))
  }
  // epilogue
  int colq = lane & 15, rowq = (lane >> 4) * 4;
  size_t ebase = (size_t)e * HD + cbase + nt * 256;
  float b1v[2][2];
#pragma unroll
  for (int jh = 0; jh < 2; ++jh)
#pragma unroll
    for (int j = 0; j < 2; ++j)
      b1v[jh][j] = b1[ebase + 128 * jh + 32 * wn + 16 * j + colq];
#pragma unroll
  for (int ih = 0; ih < 2; ++ih) {
#pragma unroll
    for (int i = 0; i < 4; ++i) {
#pragma unroll
      for (int r = 0; r < 4; ++r) {
        int grow = rt * 256 + 128 * ih + 64 * wm + 16 * i + rowq + r;
        if (grow < cnt) {
          size_t hrow = (size_t)(hoff + grow) * Hc + nt * 256;
#pragma unroll
          for (int jh = 0; jh < 2; ++jh) {
#pragma unroll
            for (int j = 0; j < 2; ++j) {
              float v = acc[ih][jh][i][j][r] + b1v[jh][j];
              float gl = 0.5f * v * (1.f + erff(v * 0.70710678118654752f));
              hbuf[hrow + 128 * jh + 32 * wn + 16 * j + colq] = (bf16)gl;
            }
          }
        }
      }
    }
  }
}

__global__ __launch_bounds__(512, 2) void gemm2_kernel(
    const bf16* __restrict__ hbuf, const bf16* __restrict__ w2t,
    const float* __restrict__ b2, const int* __restrict__ counts,
    const int* __restrict__ offsets, const int* __restrict__ tokl,
    const float* __restrict__ wgt, float* __restrict__ out,
    int Hc, int cbase, float b2scale) {
  int bid = blockIdx.x;
  int q = gridDim.x >> 3;
  int L = (bid & 7) * q + (bid >> 3);
  int rt = L & 31;
  int g = L >> 5;
  const int NT = DM / 256;  // 4
  int nt = g % NT, e = g / NT;
  int cnt = counts[e];
  if (rt * 256 >= cnt) return;
  __shared__ __align__(16) bf16 sA[2][256 * 64];
  __shared__ __align__(16) bf16 sB[2][256 * 64];
  int tid = threadIdx.x, lane = tid & 63, w = tid >> 6;
  int wm = w & 1, wn = w >> 1;
  int lf = lane & 15;
  int colx = ((lane >> 4) * 16) ^ ((lane & 7) << 4);
  int ra = tid >> 3;
  int ko = (tid & 7) * 16;
  int kox = ko ^ ((ra & 7) << 4);
  int dst = w * 1024;
  int hoff = offsets[e];
  const char* gA[4];
  const char* gB[4];
#pragma unroll
  for (int s = 0; s < 4; ++s) {
    int r = imin(rt * 256 + ra + s * 64, cnt - 1);
    gA[s] = (const char*)(hbuf + (size_t)(hoff + r) * Hc) + kox;
    int col = nt * 256 + ra + s * 64;
    gB[s] = (const char*)(w2t + ((size_t)e * DM + col) * HD + cbase) + kox;
  }
  char* Al = (char*)sA;
  char* Bl = (char*)sB;
  const char* Ab = (const char*)sA;
  const char* Bb = (const char*)sB;
  f32x4 acc[2][2][4][2];
#pragma unroll
  for (int ih = 0; ih < 2; ++ih)
#pragma unroll
    for (int jh = 0; jh < 2; ++jh)
#pragma unroll
      for (int i = 0; i < 4; ++i)
#pragma unroll
        for (int j = 0; j < 2; ++j) acc[ih][jh][i][j] = {0.f, 0.f, 0.f, 0.f};
  bf16x8 af[8], bfr0[4], bfr1[4];
  const int K = Hc / 64;
  ISSUE_A(0, 0, 0); ISSUE_B(0, 0, 0); ISSUE_B(1, 0, 0); ISSUE_A(1, 0, 0);
  VMCNT0();
  RAW_BARRIER();
  for (int k = 0; k < K; ++k) {
    int cb = (k & 1) * 32768;
    int nbo = ((k + 1) & 1) * 32768;
    int kb = (k + 1) * 128;
    KTILE_BODY(cb, nbo, kb, (k + 1 < K))
  }
  int colq = lane & 15, rowq = (lane >> 4) * 4;
  float b2v[2][2];
#pragma unroll
  for (int jh = 0; jh < 2; ++jh)
#pragma unroll
    for (int j = 0; j < 2; ++j)
      b2v[jh][j] = b2[(size_t)e * DM + nt * 256 + 128 * jh + 32 * wn + 16 * j + colq] * b2scale;
#pragma unroll
  for (int ih = 0; ih < 2; ++ih) {
#pragma unroll
    for (int i = 0; i < 4; ++i) {
#pragma unroll
      for (int r = 0; r < 4; ++r) {
        int grow = rt * 256 + 128 * ih + 64 * wm + 16 * i + rowq + r;
        if (grow < cnt) {
          float wv = wgt[e * T_TOK + grow];
          int tk = tokl[e * T_TOK + grow];
          float* orow = out + (size_t)tk * DM + nt * 256;
#pragma unroll
          for (int jh = 0; jh < 2; ++jh) {
#pragma unroll
            for (int j = 0; j < 2; ++j)
              atomicAdd(orow + 128 * jh + 32 * wn + 16 * j + colq,
                        wv * (acc[ih][jh][i][j][r] + b2v[jh][j]));
          }
        }
      }
    }
  }
}

extern "C" void kernel_launch(void* const* d_in, const int* in_sizes, int n_in,
                              void* d_out, int out_size, void* d_ws, size_t ws_size,
                              hipStream_t stream) {
  const float* x  = (const float*)d_in[0];
  const float* Wg = (const float*)d_in[1];
  const float* bg = (const float*)d_in[2];
  const float* W1 = (const float*)d_in[3];
  const float* b1 = (const float*)d_in[4];
  const float* W2 = (const float*)d_in[5];
  const float* b2 = (const float*)d_in[6];
  float* out = (float*)d_out;

  char* ws = (char*)d_ws;
  size_t off = 0;
  auto alloc = [&](size_t bytes) -> void* {
    void* p = ws + off;
    off = (off + bytes + 255) & ~(size_t)255;
    return p;
  };
  int*   counts  = (int*)alloc(NE * 4);
  int*   offsets = (int*)alloc((NE + 1) * 4);
  int*   tokl    = (int*)alloc((size_t)NE * T_TOK * 4);
  float* wgt     = (float*)alloc((size_t)NE * T_TOK * 4);
  bf16*  xbf     = (bf16*)alloc((size_t)T_TOK * DM * 2);
  bf16*  w1t     = (bf16*)alloc((size_t)NE * HD * DM * 2);
  bf16*  w2t     = (bf16*)alloc((size_t)NE * DM * HD * 2);
  size_t remain = ws_size > off ? ws_size - off : 0;
  int Hc = HD;
  while (Hc > 256 && (size_t)2 * T_TOK * Hc * 2 > remain) Hc >>= 1;  // h rows total = 2*T
  bf16* hbuf = (bf16*)alloc((size_t)2 * T_TOK * Hc * 2);

  zero_kernel<<<4096, 256, 0, stream>>>(out, counts);
  transpose_cvt_kernel<<<dim3(HD / 64, DM / 64, NE), 256, 0, stream>>>(W1, w1t, DM, HD);
  transpose_cvt_kernel<<<dim3(DM / 64, HD / 64, NE), 256, 0, stream>>>(W2, w2t, HD, DM);
  gating_kernel<<<T_TOK / 4, 256, 0, stream>>>(x, Wg, bg, counts, tokl, wgt, xbf);
  scan_kernel<<<1, 64, 0, stream>>>(counts, offsets);

  int nchunk = HD / Hc;
  for (int c = 0; c < nchunk; ++c) {
    gemm1_kernel<<<NE * (Hc / 256) * (T_TOK / 256), 512, 0, stream>>>(
        xbf, w1t, b1, counts, offsets, tokl, hbuf, Hc, c * Hc);
    gemm2_kernel<<<NE * (DM / 256) * (T_TOK / 256), 512, 0, stream>>>(
        hbuf, w2t, b2, counts, offsets, tokl, wgt, out, Hc, c * Hc, c == 0 ? 1.f : 0.f);
  }
}

// Round 7
// 1115.064 us; speedup vs baseline: 1.0226x; 1.0226x over previous
//
#include <hip/hip_runtime.h>
#include <hip/hip_bf16.h>
#include <math.h>

// Problem constants (B=4, S=2048 -> T=8192 tokens)
#define T_TOK 8192
#define DM    1024
#define NE    8
#define HD    4096

typedef __bf16 bf16;
typedef __attribute__((ext_vector_type(8))) __bf16 bf16x8;
typedef __attribute__((ext_vector_type(4))) float  f32x4;

__device__ __forceinline__ void gl_lds16(const void* g, void* l) {
  __builtin_amdgcn_global_load_lds((const __attribute__((address_space(1))) void*)g,
                                   (__attribute__((address_space(3))) void*)l, 16, 0, 0);
}

#define RAW_BARRIER() asm volatile("s_barrier" ::: "memory")
#define VMCNT0()      asm volatile("s_waitcnt vmcnt(0)" ::: "memory")

__device__ __forceinline__ int imin(int a, int b) { return a < b ? a : b; }

// ---------------- zero out + counts ----------------
__global__ void zero_kernel(float* __restrict__ out, int* __restrict__ counts) {
  size_t stride = (size_t)gridDim.x * blockDim.x;
  size_t n4 = (size_t)T_TOK * DM / 4;
  for (size_t i = (size_t)blockIdx.x * blockDim.x + threadIdx.x; i < n4; i += stride) {
    float4 z = {0.f, 0.f, 0.f, 0.f};
    ((float4*)out)[i] = z;
  }
  if (blockIdx.x == 0 && threadIdx.x < NE) counts[threadIdx.x] = 0;
}

// ---------------- transpose + cvt: in [e][R][C] fp32 -> out [e][C][R] bf16 ----------------
__global__ void transpose_cvt_kernel(const float* __restrict__ in, bf16* __restrict__ out,
                                     int R, int C) {
  __shared__ float tile[64][65];
  int e = blockIdx.z;
  int c0 = blockIdx.x * 64, r0 = blockIdx.y * 64;
  int tid = threadIdx.x;
  int lr = tid >> 2, lc = (tid & 3) * 16;
  const float* src = in + ((size_t)e * R + r0 + lr) * C + c0 + lc;
#pragma unroll
  for (int q = 0; q < 4; ++q) {
    float4 v = *(const float4*)(src + q * 4);
    tile[lr][lc + q * 4 + 0] = v.x;
    tile[lr][lc + q * 4 + 1] = v.y;
    tile[lr][lc + q * 4 + 2] = v.z;
    tile[lr][lc + q * 4 + 3] = v.w;
  }
  __syncthreads();
  int oc = tid >> 3;      // 0..31
  int rchunk = tid & 7;   // 0..7
#pragma unroll
  for (int q = 0; q < 2; ++q) {
    int ocq = oc + q * 32;
    bf16x8 o;
#pragma unroll
    for (int k = 0; k < 8; ++k) o[k] = (bf16)tile[rchunk * 8 + k][ocq];
    *(bf16x8*)(out + ((size_t)e * C + c0 + ocq) * R + r0 + rchunk * 8) = o;
  }
}

// ---------------- gating: logits (double), softmax, top-2, compaction + x->bf16 ----------------
__global__ void gating_kernel(const float* __restrict__ x, const float* __restrict__ Wg,
                              const float* __restrict__ bg, int* __restrict__ counts,
                              int* __restrict__ tokl, float* __restrict__ wgt,
                              bf16* __restrict__ xb) {
  int t = blockIdx.x * 4 + (threadIdx.x >> 6);
  int lane = threadIdx.x & 63;
  if (t >= T_TOK) return;
  double acc[NE];
#pragma unroll
  for (int e = 0; e < NE; ++e) acc[e] = 0.0;
  const float* xr = x + (size_t)t * DM;
  bf16* xbr = xb + (size_t)t * DM;
  for (int d = lane; d < DM; d += 64) {
    float xv = xr[d];
    xbr[d] = (bf16)xv;   // fused fp32->bf16 conversion
#pragma unroll
    for (int e = 0; e < NE; ++e) acc[e] += (double)xv * (double)Wg[d * NE + e];
  }
#pragma unroll
  for (int e = 0; e < NE; ++e)
    for (int o = 32; o > 0; o >>= 1) acc[e] += __shfl_down(acc[e], o, 64);
  if (lane == 0) {
    float l[NE], w[NE];
    float m = -1e30f;
#pragma unroll
    for (int e = 0; e < NE; ++e) { l[e] = (float)acc[e] + bg[e]; m = fmaxf(m, l[e]); }
    float s = 0.f;
#pragma unroll
    for (int e = 0; e < NE; ++e) { w[e] = expf(l[e] - m); s += w[e]; }
    float inv = 1.f / s;
#pragma unroll
    for (int e = 0; e < NE; ++e) w[e] *= inv;
    int e1 = 0; float v1 = w[0];
#pragma unroll
    for (int e = 1; e < NE; ++e) if (w[e] > v1) { v1 = w[e]; e1 = e; }
    int e2 = -1; float v2 = -1.f;
#pragma unroll
    for (int e = 0; e < NE; ++e) if (e != e1 && w[e] > v2) { v2 = w[e]; e2 = e; }
    int s1 = atomicAdd(&counts[e1], 1);
    tokl[e1 * T_TOK + s1] = t; wgt[e1 * T_TOK + s1] = v1;
    int s2 = atomicAdd(&counts[e2], 1);
    tokl[e2 * T_TOK + s2] = t; wgt[e2 * T_TOK + s2] = v2;
  }
}

// ---------------- scan ----------------
__global__ void scan_kernel(const int* __restrict__ counts, int* __restrict__ offsets) {
  if (threadIdx.x == 0 && blockIdx.x == 0) {
    int s = 0;
#pragma unroll
    for (int e = 0; e < NE; ++e) { offsets[e] = s; s += counts[e]; }
    offsets[NE] = s;
  }
}

// =====================================================================================
// 128x128 tile, BK=64, 256 thr (4 waves, 2x2: wm=w&1, wn=w>>1), 64 KB LDS dbuf ->
// *** 2 blocks/CU resident *** (the residency lever: r1-r6 showed every schedule at
// 1 block/CU pins at 19% MfmaUtil; m97/m114 show co-resident blocks absorb the
// vmcnt+barrier drain). Same single-barrier loop as r6 (verified): per K-tile
//   { issue 8 gl_lds for tile k+1 -> buf^1; ds_read all frags (compiler lgkmcnt);
//     setprio(1) 32 MFMA setprio(0); vmcnt(0); s_barrier; }
// WAR safe: buf^1 was last read in tile k-1 whose end-barrier completed before tile
// k's body began. Registers: acc 64 + af 32 + bfr 32 + addr ~ 175 < 256 -> 8 waves/CU.
// Staging: thread t sweeps s=0..3: LDS row (t>>3)+32s, byte (t&7)*16; source row
// rt*128+32s+(t>>3) with pre-swizzled byte kox = ko ^ ((ra&7)<<4) (T2 both-sides XOR;
// read side applies same XOR via colx) -> 0 bank conflicts (verified r1+).
// XCD-bijective map, rt fastest: expert e pinned to XCD e; B panels L2-resident.
// =====================================================================================

#define LDA_F(CB) \
  _Pragma("unroll") for (int kh = 0; kh < 2; ++kh) \
  _Pragma("unroll") for (int i = 0; i < 4; ++i) \
    af[kh*4+i] = *(const bf16x8*)(Ab + (CB) + (64*wm + 16*i + lf) * 128 + (colx ^ (kh*64)));

#define LDB_F(CB) \
  _Pragma("unroll") for (int kh = 0; kh < 2; ++kh) \
  _Pragma("unroll") for (int j = 0; j < 4; ++j) \
    bfr[kh*4+j] = *(const bf16x8*)(Bb + (CB) + (64*wn + 16*j + lf) * 128 + (colx ^ (kh*64)));

#define MM_F() \
  _Pragma("unroll") for (int kh = 0; kh < 2; ++kh) \
  _Pragma("unroll") for (int i = 0; i < 4; ++i) \
  _Pragma("unroll") for (int j = 0; j < 4; ++j) \
    acc[i][j] = __builtin_amdgcn_mfma_f32_16x16x32_bf16(af[kh*4+i], bfr[kh*4+j], acc[i][j], 0, 0, 0);

#define ISSUE_AB(NBO, KB) do { \
    _Pragma("unroll") for (int s = 0; s < 4; ++s) \
      gl_lds16(gA[s] + (KB), Al + (NBO) + s * 4096 + dst); \
    _Pragma("unroll") for (int s = 0; s < 4; ++s) \
      gl_lds16(gB[s] + (KB), Bl + (NBO) + s * 4096 + dst); \
  } while (0)

#define KTILE_BODY(CB, NBO, KB, STG) \
    if (STG) ISSUE_AB(NBO, KB); \
    LDA_F(CB); \
    LDB_F(CB); \
    __builtin_amdgcn_s_setprio(1); \
    MM_F(); \
    __builtin_amdgcn_s_setprio(0); \
    VMCNT0(); \
    RAW_BARRIER();

__global__ __launch_bounds__(256, 2) void gemm1_kernel(
    const bf16* __restrict__ xbf, const bf16* __restrict__ w1t,
    const float* __restrict__ b1, const int* __restrict__ counts,
    const int* __restrict__ offsets, const int* __restrict__ tokl,
    bf16* __restrict__ hbuf, int Hc, int cbase) {
  int bid = blockIdx.x;
  int q = gridDim.x >> 3;
  int L = (bid & 7) * q + (bid >> 3);   // bijective XCD chunk swizzle
  int rt = L & 63;                       // T_TOK/128 = 64 row tiles (fastest)
  int g = L >> 6;
  int NT = Hc >> 7;                      // col tiles this chunk
  int nt = g % NT, e = g / NT;
  int cnt = counts[e];
  if (rt * 128 >= cnt) return;
  __shared__ __align__(16) bf16 sA[2][128 * 64];
  __shared__ __align__(16) bf16 sB[2][128 * 64];
  int tid = threadIdx.x, lane = tid & 63, w = tid >> 6;
  int wm = w & 1, wn = w >> 1;
  int lf = lane & 15;
  int colx = ((lane >> 4) * 16) ^ ((lane & 7) << 4);
  int ra = tid >> 3;                     // 0..31 (row within 32-row sweep)
  int ko = (tid & 7) * 16;
  int kox = ko ^ ((ra & 7) << 4);        // pre-swizzled source byte-in-row
  int dst = w * 1024;                    // wave-uniform LDS base (+lane*16 implicit)
  int hoff = offsets[e];
  const char* gA[4];
  const char* gB[4];
#pragma unroll
  for (int s = 0; s < 4; ++s) {
    int r = imin(rt * 128 + ra + s * 32, cnt - 1);
    int t = tokl[e * T_TOK + r];
    gA[s] = (const char*)(xbf + (size_t)t * DM) + kox;
    int col = cbase + nt * 128 + ra + s * 32;
    gB[s] = (const char*)(w1t + ((size_t)e * HD + col) * DM) + kox;
  }
  char* Al = (char*)sA;
  char* Bl = (char*)sB;
  const char* Ab = (const char*)sA;
  const char* Bb = (const char*)sB;
  f32x4 acc[4][4];
#pragma unroll
  for (int i = 0; i < 4; ++i)
#pragma unroll
    for (int j = 0; j < 4; ++j) acc[i][j] = {0.f, 0.f, 0.f, 0.f};
  bf16x8 af[8], bfr[8];
  const int K = DM / 64;  // 16
  // prologue: stage tile 0 into buf 0, drain, converge
  ISSUE_AB(0, 0);
  VMCNT0();
  RAW_BARRIER();
  for (int k = 0; k < K; ++k) {
    int cb = (k & 1) * 16384;
    int nbo = ((k + 1) & 1) * 16384;
    int kb = (k + 1) * 128;
    KTILE_BODY(cb, nbo, kb, (k + 1 < K))
  }
  // epilogue
  int colq = lane & 15, rowq = (lane >> 4) * 4;
  int mw = wm * 64, nw = wn * 64;
  size_t ebase = (size_t)e * HD + cbase + nt * 128;
  float b1v[4];
#pragma unroll
  for (int j = 0; j < 4; ++j)
    b1v[j] = b1[ebase + nw + j * 16 + colq];
#pragma unroll
  for (int i = 0; i < 4; ++i) {
#pragma unroll
    for (int r = 0; r < 4; ++r) {
      int grow = rt * 128 + mw + i * 16 + rowq + r;
      if (grow < cnt) {
        size_t hrow = (size_t)(hoff + grow) * Hc + nt * 128;
#pragma unroll
        for (int j = 0; j < 4; ++j) {
          float v = acc[i][j][r] + b1v[j];
          float gl = 0.5f * v * (1.f + erff(v * 0.70710678118654752f));
          hbuf[hrow + nw + j * 16 + colq] = (bf16)gl;
        }
      }
    }
  }
}

__global__ __launch_bounds__(256, 2) void gemm2_kernel(
    const bf16* __restrict__ hbuf, const bf16* __restrict__ w2t,
    const float* __restrict__ b2, const int* __restrict__ counts,
    const int* __restrict__ offsets, const int* __restrict__ tokl,
    const float* __restrict__ wgt, float* __restrict__ out,
    int Hc, int cbase, float b2scale) {
  int bid = blockIdx.x;
  int q = gridDim.x >> 3;
  int L = (bid & 7) * q + (bid >> 3);
  int rt = L & 63;
  int g = L >> 6;
  const int NT = DM / 128;  // 8
  int nt = g % NT, e = g / NT;
  int cnt = counts[e];
  if (rt * 128 >= cnt) return;
  __shared__ __align__(16) bf16 sA[2][128 * 64];
  __shared__ __align__(16) bf16 sB[2][128 * 64];
  int tid = threadIdx.x, lane = tid & 63, w = tid >> 6;
  int wm = w & 1, wn = w >> 1;
  int lf = lane & 15;
  int colx = ((lane >> 4) * 16) ^ ((lane & 7) << 4);
  int ra = tid >> 3;
  int ko = (tid & 7) * 16;
  int kox = ko ^ ((ra & 7) << 4);
  int dst = w * 1024;
  int hoff = offsets[e];
  const char* gA[4];
  const char* gB[4];
#pragma unroll
  for (int s = 0; s < 4; ++s) {
    int r = imin(rt * 128 + ra + s * 32, cnt - 1);
    gA[s] = (const char*)(hbuf + (size_t)(hoff + r) * Hc) + kox;
    int col = nt * 128 + ra + s * 32;
    gB[s] = (const char*)(w2t + ((size_t)e * DM + col) * HD + cbase) + kox;
  }
  char* Al = (char*)sA;
  char* Bl = (char*)sB;
  const char* Ab = (const char*)sA;
  const char* Bb = (const char*)sB;
  f32x4 acc[4][4];
#pragma unroll
  for (int i = 0; i < 4; ++i)
#pragma unroll
    for (int j = 0; j < 4; ++j) acc[i][j] = {0.f, 0.f, 0.f, 0.f};
  bf16x8 af[8], bfr[8];
  const int K = Hc / 64;
  ISSUE_AB(0, 0);
  VMCNT0();
  RAW_BARRIER();
  for (int k = 0; k < K; ++k) {
    int cb = (k & 1) * 16384;
    int nbo = ((k + 1) & 1) * 16384;
    int kb = (k + 1) * 128;
    KTILE_BODY(cb, nbo, kb, (k + 1 < K))
  }
  int colq = lane & 15, rowq = (lane >> 4) * 4;
  int mw = wm * 64, nw = wn * 64;
  float b2v[4];
#pragma unroll
  for (int j = 0; j < 4; ++j)
    b2v[j] = b2[(size_t)e * DM + nt * 128 + nw + j * 16 + colq] * b2scale;
#pragma unroll
  for (int i = 0; i < 4; ++i) {
#pragma unroll
    for (int r = 0; r < 4; ++r) {
      int grow = rt * 128 + mw + i * 16 + rowq + r;
      if (grow < cnt) {
        float wv = wgt[e * T_TOK + grow];
        int tk = tokl[e * T_TOK + grow];
        float* orow = out + (size_t)tk * DM + nt * 128 + nw;
#pragma unroll
        for (int j = 0; j < 4; ++j)
          atomicAdd(orow + j * 16 + colq, wv * (acc[i][j][r] + b2v[j]));
      }
    }
  }
}

extern "C" void kernel_launch(void* const* d_in, const int* in_sizes, int n_in,
                              void* d_out, int out_size, void* d_ws, size_t ws_size,
                              hipStream_t stream) {
  const float* x  = (const float*)d_in[0];
  const float* Wg = (const float*)d_in[1];
  const float* bg = (const float*)d_in[2];
  const float* W1 = (const float*)d_in[3];
  const float* b1 = (const float*)d_in[4];
  const float* W2 = (const float*)d_in[5];
  const float* b2 = (const float*)d_in[6];
  float* out = (float*)d_out;

  char* ws = (char*)d_ws;
  size_t off = 0;
  auto alloc = [&](size_t bytes) -> void* {
    void* p = ws + off;
    off = (off + bytes + 255) & ~(size_t)255;
    return p;
  };
  int*   counts  = (int*)alloc(NE * 4);
  int*   offsets = (int*)alloc((NE + 1) * 4);
  int*   tokl    = (int*)alloc((size_t)NE * T_TOK * 4);
  float* wgt     = (float*)alloc((size_t)NE * T_TOK * 4);
  bf16*  xbf     = (bf16*)alloc((size_t)T_TOK * DM * 2);
  bf16*  w1t     = (bf16*)alloc((size_t)NE * HD * DM * 2);
  bf16*  w2t     = (bf16*)alloc((size_t)NE * DM * HD * 2);
  size_t remain = ws_size > off ? ws_size - off : 0;
  int Hc = HD;
  while (Hc > 128 && (size_t)2 * T_TOK * Hc * 2 > remain) Hc >>= 1;  // h rows total = 2*T
  bf16* hbuf = (bf16*)alloc((size_t)2 * T_TOK * Hc * 2);

  zero_kernel<<<4096, 256, 0, stream>>>(out, counts);
  transpose_cvt_kernel<<<dim3(HD / 64, DM / 64, NE), 256, 0, stream>>>(W1, w1t, DM, HD);
  transpose_cvt_kernel<<<dim3(DM / 64, HD / 64, NE), 256, 0, stream>>>(W2, w2t, HD, DM);
  gating_kernel<<<T_TOK / 4, 256, 0, stream>>>(x, Wg, bg, counts, tokl, wgt, xbf);
  scan_kernel<<<1, 64, 0, stream>>>(counts, offsets);

  int nchunk = HD / Hc;
  for (int c = 0; c < nchunk; ++c) {
    gemm1_kernel<<<NE * (Hc / 128) * (T_TOK / 128), 256, 0, stream>>>(
        xbf, w1t, b1, counts, offsets, tokl, hbuf, Hc, c * Hc);
    gemm2_kernel<<<NE * (DM / 128) * (T_TOK / 128), 256, 0, stream>>>(
        hbuf, w2t, b2, counts, offsets, tokl, wgt, out, Hc, c * Hc, c == 0 ? 1.f : 0.f);
  }
}